// Round 5
// baseline (160.985 us; speedup 1.0000x reference)
//
#include <hip/hip_runtime.h>

typedef float    f32x4  __attribute__((ext_vector_type(4)));
typedef __bf16   bf16x8 __attribute__((ext_vector_type(8)));
typedef unsigned short u16;
typedef unsigned int   u32;
typedef unsigned short u16x8 __attribute__((ext_vector_type(8)));
typedef int      i32x4  __attribute__((ext_vector_type(4)));

#define NN   8192
#define FIN  512
#define FOUT 64
#define LOG2E 1.4426950408889634f

#if __has_builtin(__builtin_amdgcn_exp2f)
#define EXP2F(x) __builtin_amdgcn_exp2f(x)
#else
#define EXP2F(x) exp2f(x)
#endif

__device__ __forceinline__ u16 f2bf(float f) {          // f32 -> bf16 RNE
    unsigned int u = __float_as_uint(f);
    u += 0x7FFFu + ((u >> 16) & 1u);
    return (u16)(u >> 16);
}
__device__ __forceinline__ float bf2f(u16 b) {
    return __uint_as_float(((unsigned int)b) << 16);
}

// ---------------------------------------------------------------------------
// K0: W (512x64 f32) -> WT_hi/WT_lo (64x512 bf16, transposed hi/lo split)
// ---------------------------------------------------------------------------
__global__ __launch_bounds__(256) void k_wt(const float* __restrict__ W,
                                            u16* __restrict__ wt_hi,
                                            u16* __restrict__ wt_lo) {
    int t = blockIdx.x * 256 + threadIdx.x;   // 0..32767
    int k = t >> 6, c = t & 63;
    float w = W[t];                            // W[k*64+c]
    u16 h = f2bf(w);
    wt_hi[c * FIN + k] = h;
    wt_lo[c * FIN + k] = f2bf(w - bf2f(h));
}

// ---------------------------------------------------------------------------
// K1 (fused): blocks 0..511   = zgemm (z=input@W via 3-term bf16 split;
//                               tiled-transposed zt; s1p/s2p pre-scaled)
//             blocks 512..16895 = adj -> bitmask pack (pure 268MB stream;
//                               runs concurrently, hides zgemm's time)
// bm[row][w] bit b = (adj[row][w*32+b] != 0);  row-stride 256 words.
// ---------------------------------------------------------------------------
__global__ __launch_bounds__(128) void k_fused(
        const float* __restrict__ in, const u16* __restrict__ wt_hi,
        const u16* __restrict__ wt_lo, const float* __restrict__ a,
        const int* __restrict__ adj, u32* __restrict__ bm,
        u16* __restrict__ zt, float* __restrict__ s1p, float* __restrict__ s2p)
{
    __shared__ f32x4 xch[4][64];

    if (blockIdx.x >= 512) {                  // ---------- pack path ----------
        const int pb  = blockIdx.x - 512;     // 0..16383
        const int row = pb >> 1, half = pb & 1;
        const int t = threadIdx.x;            // 0..127, 32 ints each
        const int* src = adj + (size_t)row * NN + half * 4096 + t * 32;
        u32 m = 0;
#pragma unroll
        for (int i = 0; i < 8; ++i) {
            const i32x4 v = __builtin_nontemporal_load((const i32x4*)(src + i * 4));
            m |= (v[0] != 0 ? 1u : 0u) << (i * 4 + 0);
            m |= (v[1] != 0 ? 1u : 0u) << (i * 4 + 1);
            m |= (v[2] != 0 ? 1u : 0u) << (i * 4 + 2);
            m |= (v[3] != 0 ? 1u : 0u) << (i * 4 + 3);
        }
        bm[(size_t)row * 256 + half * 128 + t] = m;
        return;
    }

    // ------------------------------ zgemm path ------------------------------
    const int wv = threadIdx.x >> 6;
    const int l  = threadIdx.x & 63;
    const int lr = l & 15, lk = l >> 4;
    const int row_base = blockIdx.x * 16;

    f32x4 acc[4] = {};
    const float* inrow = in + (size_t)(row_base + lr) * FIN;

    for (int ks = wv * 8; ks < wv * 8 + 8; ++ks) {
        const int k0 = ks * 32 + lk * 8;
        const f32x4 v0 = *(const f32x4*)(inrow + k0);
        const f32x4 v1 = *(const f32x4*)(inrow + k0 + 4);
        u16x8 hv, lv;
#pragma unroll
        for (int i = 0; i < 4; ++i) {
            u16 h = f2bf(v0[i]); hv[i] = h; lv[i] = f2bf(v0[i] - bf2f(h));
        }
#pragma unroll
        for (int i = 0; i < 4; ++i) {
            u16 h = f2bf(v1[i]); hv[4 + i] = h; lv[4 + i] = f2bf(v1[i] - bf2f(h));
        }
        const bf16x8 ahi = __builtin_bit_cast(bf16x8, hv);
        const bf16x8 alo = __builtin_bit_cast(bf16x8, lv);
#pragma unroll
        for (int nt = 0; nt < 4; ++nt) {
            const int wrow = nt * 16 + lr;
            const bf16x8 bh = __builtin_bit_cast(bf16x8, *(const u16x8*)(wt_hi + (size_t)wrow * FIN + k0));
            const bf16x8 bl = __builtin_bit_cast(bf16x8, *(const u16x8*)(wt_lo + (size_t)wrow * FIN + k0));
            acc[nt] = __builtin_amdgcn_mfma_f32_16x16x32_bf16(ahi, bh, acc[nt], 0, 0, 0);
            acc[nt] = __builtin_amdgcn_mfma_f32_16x16x32_bf16(alo, bh, acc[nt], 0, 0, 0);
            acc[nt] = __builtin_amdgcn_mfma_f32_16x16x32_bf16(ahi, bl, acc[nt], 0, 0, 0);
        }
    }

    if (wv == 1) {
#pragma unroll
        for (int nt = 0; nt < 4; ++nt) xch[nt][l] = acc[nt];
    }
    __syncthreads();
    if (wv == 1) return;
#pragma unroll
    for (int nt = 0; nt < 4; ++nt) acc[nt] += xch[nt][l];

    // store zt (bf16, tiled transposed): elem (j, c) -> zt[(j>>3)*512 + c*8 + (j&7)]
#pragma unroll
    for (int nt = 0; nt < 4; ++nt)
#pragma unroll
        for (int r = 0; r < 4; ++r) {
            const int j = row_base + lk * 4 + r;
            const int c = nt * 16 + lr;
            zt[(size_t)(j >> 3) * 512 + c * 8 + (j & 7)] = f2bf(acc[nt][r]);
        }

    // s1/s2 from exact accumulators
    float a1c[4], a2c[4];
#pragma unroll
    for (int nt = 0; nt < 4; ++nt) {
        a1c[nt] = a[nt * 16 + lr];
        a2c[nt] = a[64 + nt * 16 + lr];
    }
#pragma unroll
    for (int r = 0; r < 4; ++r) {
        float s1 = 0.f, s2 = 0.f;
#pragma unroll
        for (int nt = 0; nt < 4; ++nt) {
            s1 += acc[nt][r] * a1c[nt];
            s2 += acc[nt][r] * a2c[nt];
        }
#pragma unroll
        for (int m = 1; m <= 8; m <<= 1) {
            s1 += __shfl_xor(s1, m, 64);
            s2 += __shfl_xor(s2, m, 64);
        }
        if (lr == 0) {
            s1p[row_base + lk * 4 + r] = s1 * LOG2E;
            s2p[row_base + lk * 4 + r] = s2 * LOG2E;
        }
    }
}

// ---------------------------------------------------------------------------
// K3: fused masked-softmax attention + PV, reading the 8MB bitmask (L2/L3).
// 256 blocks x 512 thr (8 waves). Block = 32 rows. Wave wv owns j-slice
// [wv*32, wv*32+32) of each 256-tile; w computed in its own MFMA A-frag regs.
// Per body: [LOADZ z(N+1)] [LOADB/LOADS2 (N+1) dbuf] [PHA(N)] [MFMA(N)].
// No HBM latency anywhere in the loop; no LDS/barriers until epilogue.
// ---------------------------------------------------------------------------
#define LOADZ(Z0, Z1, Z2, Z3, jn) do {                                        \
    const u16* _zb = zq + (size_t)(((jn) + jb) >> 3) * 512;                   \
    Z0 = *(const u16x8*)(_zb +   0);                                          \
    Z1 = *(const u16x8*)(_zb + 128);                                          \
    Z2 = *(const u16x8*)(_zb + 256);                                          \
    Z3 = *(const u16x8*)(_zb + 384); } while (0)

#define LOADB(B0, B1, jn) do {                                                \
    B0 = bmr0[(jn) >> 5];                                                     \
    B1 = bmr1[(jn) >> 5]; } while (0)

#define LOADS2T(T0, T1, jn) do {                                              \
    T0 = *(const f32x4*)(s2r + (jn));                                         \
    T1 = *(const f32x4*)(s2r + (jn) + 4); } while (0)

#define PHA(WF, BW, S0, S1, S1R, DD) do {                                     \
    const u32 bsh = (BW) >> (lk * 8);                                         \
    _Pragma("unroll")                                                         \
    for (int i = 0; i < 4; ++i) {                                             \
        const float y = (S1R) + S0[i];                                        \
        float w = EXP2F(fmaxf(y, 0.2f * y));                                  \
        w = ((bsh >> i) & 1u) ? w : 0.0f;                                     \
        const __bf16 wb = (__bf16)w;                                          \
        WF[i] = wb; DD += (float)wb; }                                        \
    _Pragma("unroll")                                                         \
    for (int i = 0; i < 4; ++i) {                                             \
        const float y = (S1R) + S1[i];                                        \
        float w = EXP2F(fmaxf(y, 0.2f * y));                                  \
        w = ((bsh >> (4 + i)) & 1u) ? w : 0.0f;                               \
        const __bf16 wb = (__bf16)w;                                          \
        WF[4 + i] = wb; DD += (float)wb; } } while (0)

#define MFMA8(WF0, WF1, Z0, Z1, Z2, Z3) do {                                  \
    acc00 = __builtin_amdgcn_mfma_f32_16x16x32_bf16(WF0, __builtin_bit_cast(bf16x8, Z0), acc00, 0, 0, 0); \
    acc01 = __builtin_amdgcn_mfma_f32_16x16x32_bf16(WF0, __builtin_bit_cast(bf16x8, Z1), acc01, 0, 0, 0); \
    acc02 = __builtin_amdgcn_mfma_f32_16x16x32_bf16(WF0, __builtin_bit_cast(bf16x8, Z2), acc02, 0, 0, 0); \
    acc03 = __builtin_amdgcn_mfma_f32_16x16x32_bf16(WF0, __builtin_bit_cast(bf16x8, Z3), acc03, 0, 0, 0); \
    acc10 = __builtin_amdgcn_mfma_f32_16x16x32_bf16(WF1, __builtin_bit_cast(bf16x8, Z0), acc10, 0, 0, 0); \
    acc11 = __builtin_amdgcn_mfma_f32_16x16x32_bf16(WF1, __builtin_bit_cast(bf16x8, Z1), acc11, 0, 0, 0); \
    acc12 = __builtin_amdgcn_mfma_f32_16x16x32_bf16(WF1, __builtin_bit_cast(bf16x8, Z2), acc12, 0, 0, 0); \
    acc13 = __builtin_amdgcn_mfma_f32_16x16x32_bf16(WF1, __builtin_bit_cast(bf16x8, Z3), acc13, 0, 0, 0); } while (0)

#define BODY(CZ0, CZ1, CZ2, CZ3, NZ0, NZ1, NZ2, NZ3,                          \
             BC0, BC1, BN0, BN1, SC0, SC1, SN0, SN1, jn, DO_NEXT) do {        \
    if (DO_NEXT) LOADZ(NZ0, NZ1, NZ2, NZ3, (jn) + 256);                       \
    __builtin_amdgcn_sched_barrier(0);                                        \
    if (DO_NEXT) { LOADB(BN0, BN1, (jn) + 256);                               \
                   LOADS2T(SN0, SN1, (jn) + 256); }                           \
    bf16x8 wf0, wf1;                                                          \
    PHA(wf0, BC0, SC0, SC1, s1r0, d0);                                        \
    PHA(wf1, BC1, SC0, SC1, s1r1, d1);                                        \
    MFMA8(wf0, wf1, CZ0, CZ1, CZ2, CZ3); } while (0)

__global__ __launch_bounds__(512, 2) void k_attn(
        const u32* __restrict__ bm, const u16* __restrict__ zt,
        const float* __restrict__ s1p, const float* __restrict__ s2p,
        const float* __restrict__ bias, float* __restrict__ out)
{
    __shared__ float apart[8][32][64];   // 64 KiB (epilogue only)
    __shared__ float dpart[8][4][32];    // 4 KiB

    const int t  = threadIdx.x;
    const int wv = t >> 6, l = t & 63;
    const int lr = l & 15, lk = l >> 4;
    const int row0 = blockIdx.x * 32;
    const int jb = wv * 32 + lk * 8;     // wave+lane j offset within 256-tile

    const float s1r0 = s1p[row0 + lr];
    const float s1r1 = s1p[row0 + 16 + lr];
    const u32*   bmr0 = bm + (size_t)(row0 + lr) * 256 + wv;
    const u32*   bmr1 = bmr0 + (size_t)16 * 256;
    const float* s2r  = s2p + jb;
    const u16*   zq   = zt + lr * 8;

    f32x4 acc00{}, acc01{}, acc02{}, acc03{};
    f32x4 acc10{}, acc11{}, acc12{}, acc13{};
    float d0 = 0.f, d1 = 0.f;

    u16x8 zU0, zU1, zU2, zU3, zV0, zV1, zV2, zV3;
    u32   bA0, bA1, bB0, bB1;
    f32x4 sA0, sA1, sB0, sB1;

    LOADZ(zU0, zU1, zU2, zU3, 0);
    LOADB(bA0, bA1, 0);
    LOADS2T(sA0, sA1, 0);

    for (int jt = 0; jt < 30; jt += 2) {
        const int jn = jt * 256;
        BODY(zU0, zU1, zU2, zU3, zV0, zV1, zV2, zV3,
             bA0, bA1, bB0, bB1, sA0, sA1, sB0, sB1, jn, 1);
        BODY(zV0, zV1, zV2, zV3, zU0, zU1, zU2, zU3,
             bB0, bB1, bA0, bA1, sB0, sB1, sA0, sA1, jn + 256, 1);
    }
    BODY(zU0, zU1, zU2, zU3, zV0, zV1, zV2, zV3,
         bA0, bA1, bB0, bB1, sA0, sA1, sB0, sB1, 30 * 256, 1);
    BODY(zV0, zV1, zV2, zV3, zU0, zU1, zU2, zU3,
         bB0, bB1, bA0, bA1, sB0, sB1, sA0, sA1, 31 * 256, 0);

    // ---------------- epilogue: cross-wave j-slice reduction -----------------
    dpart[wv][lk][lr]      = d0;
    dpart[wv][lk][16 + lr] = d1;
#pragma unroll
    for (int r = 0; r < 4; ++r) {
        apart[wv][lk * 4 + r][ 0 + lr] = acc00[r];
        apart[wv][lk * 4 + r][16 + lr] = acc01[r];
        apart[wv][lk * 4 + r][32 + lr] = acc02[r];
        apart[wv][lk * 4 + r][48 + lr] = acc03[r];
        apart[wv][16 + lk * 4 + r][ 0 + lr] = acc10[r];
        apart[wv][16 + lk * 4 + r][16 + lr] = acc11[r];
        apart[wv][16 + lk * 4 + r][32 + lr] = acc12[r];
        apart[wv][16 + lk * 4 + r][48 + lr] = acc13[r];
    }
    __syncthreads();

    {
        const int r  = t >> 4;           // 0..31
        const int c0 = (t & 15) * 4;
        float den = 0.f;
#pragma unroll
        for (int q = 0; q < 32; ++q)
            den += dpart[q >> 2][q & 3][r];
        f32x4 val = {};
#pragma unroll
        for (int q = 0; q < 8; ++q)
            val += *(const f32x4*)&apart[q][r][c0];
        const f32x4 bv = *(const f32x4*)(bias + c0);
        const f32x4 o = val * (1.0f / den) + bv;
        *(f32x4*)(out + (size_t)(row0 + r) * FOUT + c0) = o;
    }
}

// ---------------------------------------------------------------------------
extern "C" void kernel_launch(void* const* d_in, const int* in_sizes, int n_in,
                              void* d_out, int out_size, void* d_ws, size_t ws_size,
                              hipStream_t stream) {
    const float* input = (const float*)d_in[0];
    const int*   adj   = (const int*)d_in[1];
    const float* W     = (const float*)d_in[2];
    const float* a     = (const float*)d_in[3];
    const float* bias  = (const float*)d_in[4];
    float* out = (float*)d_out;

    char* ws = (char*)d_ws;
    u16*   wt_hi = (u16*)ws;   ws += FIN * FOUT * sizeof(u16);
    u16*   wt_lo = (u16*)ws;   ws += FIN * FOUT * sizeof(u16);
    float* s1p   = (float*)ws; ws += NN * sizeof(float);
    float* s2p   = (float*)ws; ws += NN * sizeof(float);
    u16*   zt    = (u16*)ws;   ws += (size_t)NN * FOUT * sizeof(u16);
    u32*   bm    = (u32*)ws;   ws += (size_t)NN * (NN / 32) * sizeof(u32);   // 8 MiB

    k_wt   <<<dim3(128),           dim3(256), 0, stream>>>(W, wt_hi, wt_lo);
    k_fused<<<dim3(512 + 2 * NN),  dim3(128), 0, stream>>>(input, wt_hi, wt_lo, a,
                                                           adj, bm, zt, s1p, s2p);
    k_attn <<<dim3(256),           dim3(512), 0, stream>>>(bm, zt, s1p, s2p, bias, out);
}

// Round 6
// 92.053 us; speedup vs baseline: 1.7488x; 1.7488x over previous
//
#include <hip/hip_runtime.h>

typedef float    f32x4  __attribute__((ext_vector_type(4)));
typedef __bf16   bf16x8 __attribute__((ext_vector_type(8)));
typedef unsigned short u16;
typedef unsigned int   u32;
typedef unsigned long long u64;
typedef unsigned short u16x8 __attribute__((ext_vector_type(8)));
typedef int      i32x4  __attribute__((ext_vector_type(4)));

#define NN   8192
#define FIN  512
#define FOUT 64
#define LOG2E 1.4426950408889634f

#if __has_builtin(__builtin_amdgcn_exp2f)
#define EXP2F(x) __builtin_amdgcn_exp2f(x)
#else
#define EXP2F(x) exp2f(x)
#endif

__device__ __forceinline__ u16 f2bf(float f) {          // f32 -> bf16 RNE
    unsigned int u = __float_as_uint(f);
    u += 0x7FFFu + ((u >> 16) & 1u);
    return (u16)(u >> 16);
}
__device__ __forceinline__ float bf2f(u16 b) {
    return __uint_as_float(((unsigned int)b) << 16);
}

// ---------------------------------------------------------------------------
// K0: W (512x64 f32) -> WT_hi/WT_lo (64x512 bf16, transposed hi/lo split)
// ---------------------------------------------------------------------------
__global__ __launch_bounds__(256) void k_wt(const float* __restrict__ W,
                                            u16* __restrict__ wt_hi,
                                            u16* __restrict__ wt_lo) {
    int t = blockIdx.x * 256 + threadIdx.x;   // 0..32767
    int k = t >> 6, c = t & 63;
    float w = W[t];                            // W[k*64+c]
    u16 h = f2bf(w);
    wt_hi[c * FIN + k] = h;
    wt_lo[c * FIN + k] = f2bf(w - bf2f(h));
}

// ---------------------------------------------------------------------------
// K1 (fused): blocks 0..511    = zgemm (z=input@W via 3-term bf16 split;
//                                tiled-transposed zt; s1p/s2p pre-scaled)
//             blocks 512..8703 = adj -> bitmask pack, one row per block.
// Pack is WAVE-COALESCED: lane l loads dword col base+64k+l (256B/instr,
// 2 cachelines) and __ballot assembles the 64 mask bits in bm bit order.
// bm[row][w] bit b = (adj[row][w*32+b] != 0); row-stride 256 words.
// ---------------------------------------------------------------------------
__global__ __launch_bounds__(128) void k_fused(
        const float* __restrict__ in, const u16* __restrict__ wt_hi,
        const u16* __restrict__ wt_lo, const float* __restrict__ a,
        const int* __restrict__ adj, u32* __restrict__ bm,
        u16* __restrict__ zt, float* __restrict__ s1p, float* __restrict__ s2p)
{
    __shared__ f32x4 xch[4][64];

    if (blockIdx.x >= 512) {                  // ---------- pack path ----------
        const int row = blockIdx.x - 512;     // 0..8191
        const int wv  = threadIdx.x >> 6;     // 0..1 (wave: 4096-col half)
        const int l   = threadIdx.x & 63;
        const int* src = adj + (size_t)row * NN + wv * 4096 + l;
        u32* dst = bm + (size_t)row * 256 + wv * 128;
#pragma unroll 8
        for (int it = 0; it < 16; ++it) {
            const int base = it * 256;
            const int v0 = __builtin_nontemporal_load(src + base);
            const int v1 = __builtin_nontemporal_load(src + base + 64);
            const int v2 = __builtin_nontemporal_load(src + base + 128);
            const int v3 = __builtin_nontemporal_load(src + base + 192);
            const u64 B0 = __ballot(v0 != 0);
            const u64 B1 = __ballot(v1 != 0);
            const u64 B2 = __ballot(v2 != 0);
            const u64 B3 = __ballot(v3 != 0);
            if (l < 8) {
                const u64 Bsel = (l < 2) ? B0 : (l < 4) ? B1 : (l < 6) ? B2 : B3;
                dst[it * 8 + l] = (u32)(Bsel >> ((l & 1) * 32));
            }
        }
        return;
    }

    // ------------------------------ zgemm path ------------------------------
    const int wv = threadIdx.x >> 6;
    const int l  = threadIdx.x & 63;
    const int lr = l & 15, lk = l >> 4;
    const int row_base = blockIdx.x * 16;

    f32x4 acc[4] = {};
    const float* inrow = in + (size_t)(row_base + lr) * FIN;

    for (int ks = wv * 8; ks < wv * 8 + 8; ++ks) {
        const int k0 = ks * 32 + lk * 8;
        const f32x4 v0 = *(const f32x4*)(inrow + k0);
        const f32x4 v1 = *(const f32x4*)(inrow + k0 + 4);
        u16x8 hv, lv;
#pragma unroll
        for (int i = 0; i < 4; ++i) {
            u16 h = f2bf(v0[i]); hv[i] = h; lv[i] = f2bf(v0[i] - bf2f(h));
        }
#pragma unroll
        for (int i = 0; i < 4; ++i) {
            u16 h = f2bf(v1[i]); hv[4 + i] = h; lv[4 + i] = f2bf(v1[i] - bf2f(h));
        }
        const bf16x8 ahi = __builtin_bit_cast(bf16x8, hv);
        const bf16x8 alo = __builtin_bit_cast(bf16x8, lv);
#pragma unroll
        for (int nt = 0; nt < 4; ++nt) {
            const int wrow = nt * 16 + lr;
            const bf16x8 bh = __builtin_bit_cast(bf16x8, *(const u16x8*)(wt_hi + (size_t)wrow * FIN + k0));
            const bf16x8 bl = __builtin_bit_cast(bf16x8, *(const u16x8*)(wt_lo + (size_t)wrow * FIN + k0));
            acc[nt] = __builtin_amdgcn_mfma_f32_16x16x32_bf16(ahi, bh, acc[nt], 0, 0, 0);
            acc[nt] = __builtin_amdgcn_mfma_f32_16x16x32_bf16(alo, bh, acc[nt], 0, 0, 0);
            acc[nt] = __builtin_amdgcn_mfma_f32_16x16x32_bf16(ahi, bl, acc[nt], 0, 0, 0);
        }
    }

    if (wv == 1) {
#pragma unroll
        for (int nt = 0; nt < 4; ++nt) xch[nt][l] = acc[nt];
    }
    __syncthreads();
    if (wv == 1) return;
#pragma unroll
    for (int nt = 0; nt < 4; ++nt) acc[nt] += xch[nt][l];

    // store zt (bf16, tiled transposed): elem (j, c) -> zt[(j>>3)*512 + c*8 + (j&7)]
#pragma unroll
    for (int nt = 0; nt < 4; ++nt)
#pragma unroll
        for (int r = 0; r < 4; ++r) {
            const int j = row_base + lk * 4 + r;
            const int c = nt * 16 + lr;
            zt[(size_t)(j >> 3) * 512 + c * 8 + (j & 7)] = f2bf(acc[nt][r]);
        }

    // s1/s2 from exact accumulators
    float a1c[4], a2c[4];
#pragma unroll
    for (int nt = 0; nt < 4; ++nt) {
        a1c[nt] = a[nt * 16 + lr];
        a2c[nt] = a[64 + nt * 16 + lr];
    }
#pragma unroll
    for (int r = 0; r < 4; ++r) {
        float s1 = 0.f, s2 = 0.f;
#pragma unroll
        for (int nt = 0; nt < 4; ++nt) {
            s1 += acc[nt][r] * a1c[nt];
            s2 += acc[nt][r] * a2c[nt];
        }
#pragma unroll
        for (int m = 1; m <= 8; m <<= 1) {
            s1 += __shfl_xor(s1, m, 64);
            s2 += __shfl_xor(s2, m, 64);
        }
        if (lr == 0) {
            s1p[row_base + lk * 4 + r] = s1 * LOG2E;
            s2p[row_base + lk * 4 + r] = s2 * LOG2E;
        }
    }
}

// ---------------------------------------------------------------------------
// K3: fused masked-softmax attention + PV, reading the 8MB bitmask (cache-
// resident) instead of the 256MB adj. 256 blocks x 512 thr (8 waves).
// Block = 32 rows. Wave wv owns j-slice [wv*32, wv*32+32) of each 256-tile;
// w computed in its own MFMA A-frag regs. No LDS/barriers until epilogue.
// ---------------------------------------------------------------------------
#define LOADZ(Z0, Z1, Z2, Z3, jn) do {                                        \
    const u16* _zb = zq + (size_t)(((jn) + jb) >> 3) * 512;                   \
    Z0 = *(const u16x8*)(_zb +   0);                                          \
    Z1 = *(const u16x8*)(_zb + 128);                                          \
    Z2 = *(const u16x8*)(_zb + 256);                                          \
    Z3 = *(const u16x8*)(_zb + 384); } while (0)

#define LOADB(B0, B1, jn) do {                                                \
    B0 = bmr0[(jn) >> 5];                                                     \
    B1 = bmr1[(jn) >> 5]; } while (0)

#define LOADS2T(T0, T1, jn) do {                                              \
    T0 = *(const f32x4*)(s2r + (jn));                                         \
    T1 = *(const f32x4*)(s2r + (jn) + 4); } while (0)

#define PHA(WF, BW, S0, S1, S1R, DD) do {                                     \
    const u32 bsh = (BW) >> (lk * 8);                                         \
    _Pragma("unroll")                                                         \
    for (int i = 0; i < 4; ++i) {                                             \
        const float y = (S1R) + S0[i];                                        \
        float w = EXP2F(fmaxf(y, 0.2f * y));                                  \
        w = ((bsh >> i) & 1u) ? w : 0.0f;                                     \
        const __bf16 wb = (__bf16)w;                                          \
        WF[i] = wb; DD += (float)wb; }                                        \
    _Pragma("unroll")                                                         \
    for (int i = 0; i < 4; ++i) {                                             \
        const float y = (S1R) + S1[i];                                        \
        float w = EXP2F(fmaxf(y, 0.2f * y));                                  \
        w = ((bsh >> (4 + i)) & 1u) ? w : 0.0f;                               \
        const __bf16 wb = (__bf16)w;                                          \
        WF[4 + i] = wb; DD += (float)wb; } } while (0)

#define MFMA8(WF0, WF1, Z0, Z1, Z2, Z3) do {                                  \
    acc00 = __builtin_amdgcn_mfma_f32_16x16x32_bf16(WF0, __builtin_bit_cast(bf16x8, Z0), acc00, 0, 0, 0); \
    acc01 = __builtin_amdgcn_mfma_f32_16x16x32_bf16(WF0, __builtin_bit_cast(bf16x8, Z1), acc01, 0, 0, 0); \
    acc02 = __builtin_amdgcn_mfma_f32_16x16x32_bf16(WF0, __builtin_bit_cast(bf16x8, Z2), acc02, 0, 0, 0); \
    acc03 = __builtin_amdgcn_mfma_f32_16x16x32_bf16(WF0, __builtin_bit_cast(bf16x8, Z3), acc03, 0, 0, 0); \
    acc10 = __builtin_amdgcn_mfma_f32_16x16x32_bf16(WF1, __builtin_bit_cast(bf16x8, Z0), acc10, 0, 0, 0); \
    acc11 = __builtin_amdgcn_mfma_f32_16x16x32_bf16(WF1, __builtin_bit_cast(bf16x8, Z1), acc11, 0, 0, 0); \
    acc12 = __builtin_amdgcn_mfma_f32_16x16x32_bf16(WF1, __builtin_bit_cast(bf16x8, Z2), acc12, 0, 0, 0); \
    acc13 = __builtin_amdgcn_mfma_f32_16x16x32_bf16(WF1, __builtin_bit_cast(bf16x8, Z3), acc13, 0, 0, 0); } while (0)

#define BODY(CZ0, CZ1, CZ2, CZ3, NZ0, NZ1, NZ2, NZ3,                          \
             BC0, BC1, BN0, BN1, SC0, SC1, SN0, SN1, jn, DO_NEXT) do {        \
    if (DO_NEXT) LOADZ(NZ0, NZ1, NZ2, NZ3, (jn) + 256);                       \
    __builtin_amdgcn_sched_barrier(0);                                        \
    if (DO_NEXT) { LOADB(BN0, BN1, (jn) + 256);                               \
                   LOADS2T(SN0, SN1, (jn) + 256); }                           \
    bf16x8 wf0, wf1;                                                          \
    PHA(wf0, BC0, SC0, SC1, s1r0, d0);                                        \
    PHA(wf1, BC1, SC0, SC1, s1r1, d1);                                        \
    MFMA8(wf0, wf1, CZ0, CZ1, CZ2, CZ3); } while (0)

__global__ __launch_bounds__(512, 2) void k_attn(
        const u32* __restrict__ bm, const u16* __restrict__ zt,
        const float* __restrict__ s1p, const float* __restrict__ s2p,
        const float* __restrict__ bias, float* __restrict__ out)
{
    __shared__ float apart[8][32][64];   // 64 KiB (epilogue only)
    __shared__ float dpart[8][4][32];    // 4 KiB

    const int t  = threadIdx.x;
    const int wv = t >> 6, l = t & 63;
    const int lr = l & 15, lk = l >> 4;
    const int row0 = blockIdx.x * 32;
    const int jb = wv * 32 + lk * 8;     // wave+lane j offset within 256-tile

    const float s1r0 = s1p[row0 + lr];
    const float s1r1 = s1p[row0 + 16 + lr];
    const u32*   bmr0 = bm + (size_t)(row0 + lr) * 256 + wv;
    const u32*   bmr1 = bmr0 + (size_t)16 * 256;
    const float* s2r  = s2p + jb;
    const u16*   zq   = zt + lr * 8;

    f32x4 acc00{}, acc01{}, acc02{}, acc03{};
    f32x4 acc10{}, acc11{}, acc12{}, acc13{};
    float d0 = 0.f, d1 = 0.f;

    u16x8 zU0, zU1, zU2, zU3, zV0, zV1, zV2, zV3;
    u32   bA0, bA1, bB0, bB1;
    f32x4 sA0, sA1, sB0, sB1;

    LOADZ(zU0, zU1, zU2, zU3, 0);
    LOADB(bA0, bA1, 0);
    LOADS2T(sA0, sA1, 0);

    for (int jt = 0; jt < 30; jt += 2) {
        const int jn = jt * 256;
        BODY(zU0, zU1, zU2, zU3, zV0, zV1, zV2, zV3,
             bA0, bA1, bB0, bB1, sA0, sA1, sB0, sB1, jn, 1);
        BODY(zV0, zV1, zV2, zV3, zU0, zU1, zU2, zU3,
             bB0, bB1, bA0, bA1, sB0, sB1, sA0, sA1, jn + 256, 1);
    }
    BODY(zU0, zU1, zU2, zU3, zV0, zV1, zV2, zV3,
         bA0, bA1, bB0, bB1, sA0, sA1, sB0, sB1, 30 * 256, 1);
    BODY(zV0, zV1, zV2, zV3, zU0, zU1, zU2, zU3,
         bB0, bB1, bA0, bA1, sB0, sB1, sA0, sA1, 31 * 256, 0);

    // ---------------- epilogue: cross-wave j-slice reduction -----------------
    dpart[wv][lk][lr]      = d0;
    dpart[wv][lk][16 + lr] = d1;
#pragma unroll
    for (int r = 0; r < 4; ++r) {
        apart[wv][lk * 4 + r][ 0 + lr] = acc00[r];
        apart[wv][lk * 4 + r][16 + lr] = acc01[r];
        apart[wv][lk * 4 + r][32 + lr] = acc02[r];
        apart[wv][lk * 4 + r][48 + lr] = acc03[r];
        apart[wv][16 + lk * 4 + r][ 0 + lr] = acc10[r];
        apart[wv][16 + lk * 4 + r][16 + lr] = acc11[r];
        apart[wv][16 + lk * 4 + r][32 + lr] = acc12[r];
        apart[wv][16 + lk * 4 + r][48 + lr] = acc13[r];
    }
    __syncthreads();

    {
        const int r  = t >> 4;           // 0..31
        const int c0 = (t & 15) * 4;
        float den = 0.f;
#pragma unroll
        for (int q = 0; q < 32; ++q)
            den += dpart[q >> 2][q & 3][r];
        f32x4 val = {};
#pragma unroll
        for (int q = 0; q < 8; ++q)
            val += *(const f32x4*)&apart[q][r][c0];
        const f32x4 bv = *(const f32x4*)(bias + c0);
        const f32x4 o = val * (1.0f / den) + bv;
        *(f32x4*)(out + (size_t)(row0 + r) * FOUT + c0) = o;
    }
}

// ---------------------------------------------------------------------------
extern "C" void kernel_launch(void* const* d_in, const int* in_sizes, int n_in,
                              void* d_out, int out_size, void* d_ws, size_t ws_size,
                              hipStream_t stream) {
    const float* input = (const float*)d_in[0];
    const int*   adj   = (const int*)d_in[1];
    const float* W     = (const float*)d_in[2];
    const float* a     = (const float*)d_in[3];
    const float* bias  = (const float*)d_in[4];
    float* out = (float*)d_out;

    char* ws = (char*)d_ws;
    u16*   wt_hi = (u16*)ws;   ws += FIN * FOUT * sizeof(u16);
    u16*   wt_lo = (u16*)ws;   ws += FIN * FOUT * sizeof(u16);
    float* s1p   = (float*)ws; ws += NN * sizeof(float);
    float* s2p   = (float*)ws; ws += NN * sizeof(float);
    u16*   zt    = (u16*)ws;   ws += (size_t)NN * FOUT * sizeof(u16);
    u32*   bm    = (u32*)ws;   ws += (size_t)NN * (NN / 32) * sizeof(u32);   // 8 MiB

    k_wt   <<<dim3(128),      dim3(256), 0, stream>>>(W, wt_hi, wt_lo);
    k_fused<<<dim3(512 + NN), dim3(128), 0, stream>>>(input, wt_hi, wt_lo, a,
                                                      adj, bm, zt, s1p, s2p);
    k_attn <<<dim3(256),      dim3(512), 0, stream>>>(bm, zt, s1p, s2p, bias, out);
}

// Round 7
// 88.484 us; speedup vs baseline: 1.8194x; 1.0403x over previous
//
#include <hip/hip_runtime.h>

typedef float    f32x4  __attribute__((ext_vector_type(4)));
typedef __bf16   bf16x8 __attribute__((ext_vector_type(8)));
typedef unsigned short u16;
typedef unsigned int   u32;
typedef unsigned long long u64;
typedef unsigned short u16x8 __attribute__((ext_vector_type(8)));
typedef int      i32x4  __attribute__((ext_vector_type(4)));

#define NN   8192
#define FIN  512
#define FOUT 64
#define LOG2E 1.4426950408889634f

#if __has_builtin(__builtin_amdgcn_exp2f)
#define EXP2F(x) __builtin_amdgcn_exp2f(x)
#else
#define EXP2F(x) exp2f(x)
#endif

__device__ __forceinline__ u16 f2bf(float f) {          // f32 -> bf16 RNE
    unsigned int u = __float_as_uint(f);
    u += 0x7FFFu + ((u >> 16) & 1u);
    return (u16)(u >> 16);
}
__device__ __forceinline__ float bf2f(u16 b) {
    return __uint_as_float(((unsigned int)b) << 16);
}
__device__ __forceinline__ u32 spread4(u32 x) {         // byte bit q -> bit 4q
    x = (x | (x << 12)) & 0x000F000Fu;
    x = (x | (x <<  6)) & 0x03030303u;
    x = (x | (x <<  3)) & 0x11111111u;
    return x;
}

// ---------------------------------------------------------------------------
// K0: W (512x64 f32) -> WT_hi/WT_lo (64x512 bf16, transposed hi/lo split)
// ---------------------------------------------------------------------------
__global__ __launch_bounds__(256) void k_wt(const float* __restrict__ W,
                                            u16* __restrict__ wt_hi,
                                            u16* __restrict__ wt_lo) {
    int t = blockIdx.x * 256 + threadIdx.x;   // 0..32767
    int k = t >> 6, c = t & 63;
    float w = W[t];                            // W[k*64+c]
    u16 h = f2bf(w);
    wt_hi[c * FIN + k] = h;
    wt_lo[c * FIN + k] = f2bf(w - bf2f(h));
}

// ---------------------------------------------------------------------------
// K1 (fused): blocks 0..511    = zgemm (z=input@W via 3-term bf16 split;
//                                tiled-transposed zt; s1p/s2p pre-scaled)
//             blocks 512..8703 = adj -> bitmask pack, one row per block.
// Pack reads i32x4/lane (16B/lane = 1KB/instr, the m13-proven stream shape,
// plain loads). B_k = ballot(v[k]!=0) has bit l = col 4l+k; lanes 0..7
// rebuild bm words (bit b of word w = col 32w+b) via spread4 interleave.
// bm[row][w] bit b = (adj[row][w*32+b] != 0); row-stride 256 words.
// ---------------------------------------------------------------------------
__global__ __launch_bounds__(128) void k_fused(
        const float* __restrict__ in, const u16* __restrict__ wt_hi,
        const u16* __restrict__ wt_lo, const float* __restrict__ a,
        const int* __restrict__ adj, u32* __restrict__ bm,
        u16* __restrict__ zt, float* __restrict__ s1p, float* __restrict__ s2p)
{
    __shared__ f32x4 xch[4][64];

    if (blockIdx.x >= 512) {                  // ---------- pack path ----------
        const int row = blockIdx.x - 512;     // 0..8191
        const int wv  = threadIdx.x >> 6;     // 0..1 (wave: 4096-col half)
        const int l   = threadIdx.x & 63;
        const int* src = adj + (size_t)row * NN + wv * 4096 + l * 4;
        u32* dst = bm + (size_t)row * 256 + wv * 128;
#pragma unroll 8
        for (int it = 0; it < 16; ++it) {
            const i32x4 v = *(const i32x4*)(src + it * 256);  // cols it*256+4l+e
            const u64 B0 = __ballot(v[0] != 0);   // bit l = col 4l+0
            const u64 B1 = __ballot(v[1] != 0);   // bit l = col 4l+1
            const u64 B2 = __ballot(v[2] != 0);   // bit l = col 4l+2
            const u64 B3 = __ballot(v[3] != 0);   // bit l = col 4l+3
            if (l < 8) {
                const u32 b0 = (u32)(B0 >> (l * 8)) & 0xFFu;
                const u32 b1 = (u32)(B1 >> (l * 8)) & 0xFFu;
                const u32 b2 = (u32)(B2 >> (l * 8)) & 0xFFu;
                const u32 b3 = (u32)(B3 >> (l * 8)) & 0xFFu;
                dst[it * 8 + l] = spread4(b0) | (spread4(b1) << 1)
                                | (spread4(b2) << 2) | (spread4(b3) << 3);
            }
        }
        return;
    }

    // ------------------------------ zgemm path ------------------------------
    const int wv = threadIdx.x >> 6;
    const int l  = threadIdx.x & 63;
    const int lr = l & 15, lk = l >> 4;
    const int row_base = blockIdx.x * 16;

    f32x4 acc[4] = {};
    const float* inrow = in + (size_t)(row_base + lr) * FIN;

    for (int ks = wv * 8; ks < wv * 8 + 8; ++ks) {
        const int k0 = ks * 32 + lk * 8;
        const f32x4 v0 = *(const f32x4*)(inrow + k0);
        const f32x4 v1 = *(const f32x4*)(inrow + k0 + 4);
        u16x8 hv, lv;
#pragma unroll
        for (int i = 0; i < 4; ++i) {
            u16 h = f2bf(v0[i]); hv[i] = h; lv[i] = f2bf(v0[i] - bf2f(h));
        }
#pragma unroll
        for (int i = 0; i < 4; ++i) {
            u16 h = f2bf(v1[i]); hv[4 + i] = h; lv[4 + i] = f2bf(v1[i] - bf2f(h));
        }
        const bf16x8 ahi = __builtin_bit_cast(bf16x8, hv);
        const bf16x8 alo = __builtin_bit_cast(bf16x8, lv);
#pragma unroll
        for (int nt = 0; nt < 4; ++nt) {
            const int wrow = nt * 16 + lr;
            const bf16x8 bh = __builtin_bit_cast(bf16x8, *(const u16x8*)(wt_hi + (size_t)wrow * FIN + k0));
            const bf16x8 bl = __builtin_bit_cast(bf16x8, *(const u16x8*)(wt_lo + (size_t)wrow * FIN + k0));
            acc[nt] = __builtin_amdgcn_mfma_f32_16x16x32_bf16(ahi, bh, acc[nt], 0, 0, 0);
            acc[nt] = __builtin_amdgcn_mfma_f32_16x16x32_bf16(alo, bh, acc[nt], 0, 0, 0);
            acc[nt] = __builtin_amdgcn_mfma_f32_16x16x32_bf16(ahi, bl, acc[nt], 0, 0, 0);
        }
    }

    if (wv == 1) {
#pragma unroll
        for (int nt = 0; nt < 4; ++nt) xch[nt][l] = acc[nt];
    }
    __syncthreads();
    if (wv == 1) return;
#pragma unroll
    for (int nt = 0; nt < 4; ++nt) acc[nt] += xch[nt][l];

    // store zt (bf16, tiled transposed): elem (j, c) -> zt[(j>>3)*512 + c*8 + (j&7)]
#pragma unroll
    for (int nt = 0; nt < 4; ++nt)
#pragma unroll
        for (int r = 0; r < 4; ++r) {
            const int j = row_base + lk * 4 + r;
            const int c = nt * 16 + lr;
            zt[(size_t)(j >> 3) * 512 + c * 8 + (j & 7)] = f2bf(acc[nt][r]);
        }

    // s1/s2 from exact accumulators
    float a1c[4], a2c[4];
#pragma unroll
    for (int nt = 0; nt < 4; ++nt) {
        a1c[nt] = a[nt * 16 + lr];
        a2c[nt] = a[64 + nt * 16 + lr];
    }
#pragma unroll
    for (int r = 0; r < 4; ++r) {
        float s1 = 0.f, s2 = 0.f;
#pragma unroll
        for (int nt = 0; nt < 4; ++nt) {
            s1 += acc[nt][r] * a1c[nt];
            s2 += acc[nt][r] * a2c[nt];
        }
#pragma unroll
        for (int m = 1; m <= 8; m <<= 1) {
            s1 += __shfl_xor(s1, m, 64);
            s2 += __shfl_xor(s2, m, 64);
        }
        if (lr == 0) {
            s1p[row_base + lk * 4 + r] = s1 * LOG2E;
            s2p[row_base + lk * 4 + r] = s2 * LOG2E;
        }
    }
}

// ---------------------------------------------------------------------------
// K3: fused masked-softmax attention + PV, reading the 8MB bitmask (cache-
// resident) instead of the 256MB adj. 256 blocks x 512 thr (8 waves).
// Block = 32 rows. Wave wv owns j-slice [wv*32, wv*32+32) of each 256-tile;
// w computed in its own MFMA A-frag regs. No LDS/barriers until epilogue.
// ---------------------------------------------------------------------------
#define LOADZ(Z0, Z1, Z2, Z3, jn) do {                                        \
    const u16* _zb = zq + (size_t)(((jn) + jb) >> 3) * 512;                   \
    Z0 = *(const u16x8*)(_zb +   0);                                          \
    Z1 = *(const u16x8*)(_zb + 128);                                          \
    Z2 = *(const u16x8*)(_zb + 256);                                          \
    Z3 = *(const u16x8*)(_zb + 384); } while (0)

#define LOADB(B0, B1, jn) do {                                                \
    B0 = bmr0[(jn) >> 5];                                                     \
    B1 = bmr1[(jn) >> 5]; } while (0)

#define LOADS2T(T0, T1, jn) do {                                              \
    T0 = *(const f32x4*)(s2r + (jn));                                         \
    T1 = *(const f32x4*)(s2r + (jn) + 4); } while (0)

#define PHA(WF, BW, S0, S1, S1R, DD) do {                                     \
    const u32 bsh = (BW) >> (lk * 8);                                         \
    _Pragma("unroll")                                                         \
    for (int i = 0; i < 4; ++i) {                                             \
        const float y = (S1R) + S0[i];                                        \
        float w = EXP2F(fmaxf(y, 0.2f * y));                                  \
        w = ((bsh >> i) & 1u) ? w : 0.0f;                                     \
        const __bf16 wb = (__bf16)w;                                          \
        WF[i] = wb; DD += (float)wb; }                                        \
    _Pragma("unroll")                                                         \
    for (int i = 0; i < 4; ++i) {                                             \
        const float y = (S1R) + S1[i];                                        \
        float w = EXP2F(fmaxf(y, 0.2f * y));                                  \
        w = ((bsh >> (4 + i)) & 1u) ? w : 0.0f;                               \
        const __bf16 wb = (__bf16)w;                                          \
        WF[4 + i] = wb; DD += (float)wb; } } while (0)

#define MFMA8(WF0, WF1, Z0, Z1, Z2, Z3) do {                                  \
    acc00 = __builtin_amdgcn_mfma_f32_16x16x32_bf16(WF0, __builtin_bit_cast(bf16x8, Z0), acc00, 0, 0, 0); \
    acc01 = __builtin_amdgcn_mfma_f32_16x16x32_bf16(WF0, __builtin_bit_cast(bf16x8, Z1), acc01, 0, 0, 0); \
    acc02 = __builtin_amdgcn_mfma_f32_16x16x32_bf16(WF0, __builtin_bit_cast(bf16x8, Z2), acc02, 0, 0, 0); \
    acc03 = __builtin_amdgcn_mfma_f32_16x16x32_bf16(WF0, __builtin_bit_cast(bf16x8, Z3), acc03, 0, 0, 0); \
    acc10 = __builtin_amdgcn_mfma_f32_16x16x32_bf16(WF1, __builtin_bit_cast(bf16x8, Z0), acc10, 0, 0, 0); \
    acc11 = __builtin_amdgcn_mfma_f32_16x16x32_bf16(WF1, __builtin_bit_cast(bf16x8, Z1), acc11, 0, 0, 0); \
    acc12 = __builtin_amdgcn_mfma_f32_16x16x32_bf16(WF1, __builtin_bit_cast(bf16x8, Z2), acc12, 0, 0, 0); \
    acc13 = __builtin_amdgcn_mfma_f32_16x16x32_bf16(WF1, __builtin_bit_cast(bf16x8, Z3), acc13, 0, 0, 0); } while (0)

#define BODY(CZ0, CZ1, CZ2, CZ3, NZ0, NZ1, NZ2, NZ3,                          \
             BC0, BC1, BN0, BN1, SC0, SC1, SN0, SN1, jn, DO_NEXT) do {        \
    if (DO_NEXT) LOADZ(NZ0, NZ1, NZ2, NZ3, (jn) + 256);                       \
    __builtin_amdgcn_sched_barrier(0);                                        \
    if (DO_NEXT) { LOADB(BN0, BN1, (jn) + 256);                               \
                   LOADS2T(SN0, SN1, (jn) + 256); }                           \
    bf16x8 wf0, wf1;                                                          \
    PHA(wf0, BC0, SC0, SC1, s1r0, d0);                                        \
    PHA(wf1, BC1, SC0, SC1, s1r1, d1);                                        \
    MFMA8(wf0, wf1, CZ0, CZ1, CZ2, CZ3); } while (0)

__global__ __launch_bounds__(512, 2) void k_attn(
        const u32* __restrict__ bm, const u16* __restrict__ zt,
        const float* __restrict__ s1p, const float* __restrict__ s2p,
        const float* __restrict__ bias, float* __restrict__ out)
{
    __shared__ float apart[8][32][64];   // 64 KiB (epilogue only)
    __shared__ float dpart[8][4][32];    // 4 KiB

    const int t  = threadIdx.x;
    const int wv = t >> 6, l = t & 63;
    const int lr = l & 15, lk = l >> 4;
    const int row0 = blockIdx.x * 32;
    const int jb = wv * 32 + lk * 8;     // wave+lane j offset within 256-tile

    const float s1r0 = s1p[row0 + lr];
    const float s1r1 = s1p[row0 + 16 + lr];
    const u32*   bmr0 = bm + (size_t)(row0 + lr) * 256 + wv;
    const u32*   bmr1 = bmr0 + (size_t)16 * 256;
    const float* s2r  = s2p + jb;
    const u16*   zq   = zt + lr * 8;

    f32x4 acc00{}, acc01{}, acc02{}, acc03{};
    f32x4 acc10{}, acc11{}, acc12{}, acc13{};
    float d0 = 0.f, d1 = 0.f;

    u16x8 zU0, zU1, zU2, zU3, zV0, zV1, zV2, zV3;
    u32   bA0, bA1, bB0, bB1;
    f32x4 sA0, sA1, sB0, sB1;

    LOADZ(zU0, zU1, zU2, zU3, 0);
    LOADB(bA0, bA1, 0);
    LOADS2T(sA0, sA1, 0);

    for (int jt = 0; jt < 30; jt += 2) {
        const int jn = jt * 256;
        BODY(zU0, zU1, zU2, zU3, zV0, zV1, zV2, zV3,
             bA0, bA1, bB0, bB1, sA0, sA1, sB0, sB1, jn, 1);
        BODY(zV0, zV1, zV2, zV3, zU0, zU1, zU2, zU3,
             bB0, bB1, bA0, bA1, sB0, sB1, sA0, sA1, jn + 256, 1);
    }
    BODY(zU0, zU1, zU2, zU3, zV0, zV1, zV2, zV3,
         bA0, bA1, bB0, bB1, sA0, sA1, sB0, sB1, 30 * 256, 1);
    BODY(zV0, zV1, zV2, zV3, zU0, zU1, zU2, zU3,
         bB0, bB1, bA0, bA1, sB0, sB1, sA0, sA1, 31 * 256, 0);

    // ---------------- epilogue: cross-wave j-slice reduction -----------------
    dpart[wv][lk][lr]      = d0;
    dpart[wv][lk][16 + lr] = d1;
#pragma unroll
    for (int r = 0; r < 4; ++r) {
        apart[wv][lk * 4 + r][ 0 + lr] = acc00[r];
        apart[wv][lk * 4 + r][16 + lr] = acc01[r];
        apart[wv][lk * 4 + r][32 + lr] = acc02[r];
        apart[wv][lk * 4 + r][48 + lr] = acc03[r];
        apart[wv][16 + lk * 4 + r][ 0 + lr] = acc10[r];
        apart[wv][16 + lk * 4 + r][16 + lr] = acc11[r];
        apart[wv][16 + lk * 4 + r][32 + lr] = acc12[r];
        apart[wv][16 + lk * 4 + r][48 + lr] = acc13[r];
    }
    __syncthreads();

    {
        const int r  = t >> 4;           // 0..31
        const int c0 = (t & 15) * 4;
        float den = 0.f;
#pragma unroll
        for (int q = 0; q < 32; ++q)
            den += dpart[q >> 2][q & 3][r];
        f32x4 val = {};
#pragma unroll
        for (int q = 0; q < 8; ++q)
            val += *(const f32x4*)&apart[q][r][c0];
        const f32x4 bv = *(const f32x4*)(bias + c0);
        const f32x4 o = val * (1.0f / den) + bv;
        *(f32x4*)(out + (size_t)(row0 + r) * FOUT + c0) = o;
    }
}

// ---------------------------------------------------------------------------
extern "C" void kernel_launch(void* const* d_in, const int* in_sizes, int n_in,
                              void* d_out, int out_size, void* d_ws, size_t ws_size,
                              hipStream_t stream) {
    const float* input = (const float*)d_in[0];
    const int*   adj   = (const int*)d_in[1];
    const float* W     = (const float*)d_in[2];
    const float* a     = (const float*)d_in[3];
    const float* bias  = (const float*)d_in[4];
    float* out = (float*)d_out;

    char* ws = (char*)d_ws;
    u16*   wt_hi = (u16*)ws;   ws += FIN * FOUT * sizeof(u16);
    u16*   wt_lo = (u16*)ws;   ws += FIN * FOUT * sizeof(u16);
    float* s1p   = (float*)ws; ws += NN * sizeof(float);
    float* s2p   = (float*)ws; ws += NN * sizeof(float);
    u16*   zt    = (u16*)ws;   ws += (size_t)NN * FOUT * sizeof(u16);
    u32*   bm    = (u32*)ws;   ws += (size_t)NN * (NN / 32) * sizeof(u32);   // 8 MiB

    k_wt   <<<dim3(128),      dim3(256), 0, stream>>>(W, wt_hi, wt_lo);
    k_fused<<<dim3(512 + NN), dim3(128), 0, stream>>>(input, wt_hi, wt_lo, a,
                                                      adj, bm, zt, s1p, s2p);
    k_attn <<<dim3(256),      dim3(512), 0, stream>>>(bm, zt, s1p, s2p, bias, out);
}

// Round 8
// 81.235 us; speedup vs baseline: 1.9817x; 1.0892x over previous
//
#include <hip/hip_runtime.h>

typedef float    f32x4  __attribute__((ext_vector_type(4)));
typedef __bf16   bf16x8 __attribute__((ext_vector_type(8)));
typedef unsigned short u16;
typedef unsigned int   u32;
typedef unsigned long long u64;
typedef unsigned short u16x8 __attribute__((ext_vector_type(8)));
typedef int      i32x4  __attribute__((ext_vector_type(4)));

#define NN   8192
#define FIN  512
#define FOUT 64
#define LOG2E 1.4426950408889634f

#if __has_builtin(__builtin_amdgcn_exp2f)
#define EXP2F(x) __builtin_amdgcn_exp2f(x)
#else
#define EXP2F(x) exp2f(x)
#endif

__device__ __forceinline__ u16 f2bf(float f) {          // f32 -> bf16 RNE
    unsigned int u = __float_as_uint(f);
    u += 0x7FFFu + ((u >> 16) & 1u);
    return (u16)(u >> 16);
}
__device__ __forceinline__ float bf2f(u16 b) {
    return __uint_as_float(((unsigned int)b) << 16);
}
__device__ __forceinline__ u32 spread4(u32 x) {         // byte bit q -> bit 4q
    x = (x | (x << 12)) & 0x000F000Fu;
    x = (x | (x <<  6)) & 0x03030303u;
    x = (x | (x <<  3)) & 0x11111111u;
    return x;
}

// ---------------------------------------------------------------------------
// K0: W (512x64 f32) -> WT_hi/WT_lo (64x512 bf16, transposed hi/lo split)
// ---------------------------------------------------------------------------
__global__ __launch_bounds__(256) void k_wt(const float* __restrict__ W,
                                            u16* __restrict__ wt_hi,
                                            u16* __restrict__ wt_lo) {
    int t = blockIdx.x * 256 + threadIdx.x;   // 0..32767
    int k = t >> 6, c = t & 63;
    float w = W[t];                            // W[k*64+c]
    u16 h = f2bf(w);
    wt_hi[c * FIN + k] = h;
    wt_lo[c * FIN + k] = f2bf(w - bf2f(h));
}

// ---------------------------------------------------------------------------
// K1: z = input @ W (3-term bf16 MFMA split ~ f32-exact), then:
//   - zt (bf16, TILED transposed layout [j/8][c<64][j&7]) from accumulators
//   - s1p = (z@a1)*log2e, s2p = (z@a2)*log2e from f32 accumulators
// grid 512 x 128thr: block = one 16-row m-tile, 2 waves K-split.
// ---------------------------------------------------------------------------
__global__ __launch_bounds__(128) void k_zgemm(
        const float* __restrict__ in, const u16* __restrict__ wt_hi,
        const u16* __restrict__ wt_lo, const float* __restrict__ a,
        u16* __restrict__ zt, float* __restrict__ s1p, float* __restrict__ s2p)
{
    __shared__ f32x4 xch[4][64];
    const int wv = threadIdx.x >> 6;
    const int l  = threadIdx.x & 63;
    const int lr = l & 15, lk = l >> 4;
    const int row_base = blockIdx.x * 16;

    f32x4 acc[4] = {};
    const float* inrow = in + (size_t)(row_base + lr) * FIN;

    for (int ks = wv * 8; ks < wv * 8 + 8; ++ks) {
        const int k0 = ks * 32 + lk * 8;
        const f32x4 v0 = *(const f32x4*)(inrow + k0);
        const f32x4 v1 = *(const f32x4*)(inrow + k0 + 4);
        u16x8 hv, lv;
#pragma unroll
        for (int i = 0; i < 4; ++i) {
            u16 h = f2bf(v0[i]); hv[i] = h; lv[i] = f2bf(v0[i] - bf2f(h));
        }
#pragma unroll
        for (int i = 0; i < 4; ++i) {
            u16 h = f2bf(v1[i]); hv[4 + i] = h; lv[4 + i] = f2bf(v1[i] - bf2f(h));
        }
        const bf16x8 ahi = __builtin_bit_cast(bf16x8, hv);
        const bf16x8 alo = __builtin_bit_cast(bf16x8, lv);
#pragma unroll
        for (int nt = 0; nt < 4; ++nt) {
            const int wrow = nt * 16 + lr;
            const bf16x8 bh = __builtin_bit_cast(bf16x8, *(const u16x8*)(wt_hi + (size_t)wrow * FIN + k0));
            const bf16x8 bl = __builtin_bit_cast(bf16x8, *(const u16x8*)(wt_lo + (size_t)wrow * FIN + k0));
            acc[nt] = __builtin_amdgcn_mfma_f32_16x16x32_bf16(ahi, bh, acc[nt], 0, 0, 0);
            acc[nt] = __builtin_amdgcn_mfma_f32_16x16x32_bf16(alo, bh, acc[nt], 0, 0, 0);
            acc[nt] = __builtin_amdgcn_mfma_f32_16x16x32_bf16(ahi, bl, acc[nt], 0, 0, 0);
        }
    }

    if (wv == 1) {
#pragma unroll
        for (int nt = 0; nt < 4; ++nt) xch[nt][l] = acc[nt];
    }
    __syncthreads();
    if (wv == 1) return;
#pragma unroll
    for (int nt = 0; nt < 4; ++nt) acc[nt] += xch[nt][l];

    // store zt (bf16, tiled transposed): elem (j, c) -> zt[(j>>3)*512 + c*8 + (j&7)]
#pragma unroll
    for (int nt = 0; nt < 4; ++nt)
#pragma unroll
        for (int r = 0; r < 4; ++r) {
            const int j = row_base + lk * 4 + r;
            const int c = nt * 16 + lr;
            zt[(size_t)(j >> 3) * 512 + c * 8 + (j & 7)] = f2bf(acc[nt][r]);
        }

    // s1/s2 from exact accumulators
    float a1c[4], a2c[4];
#pragma unroll
    for (int nt = 0; nt < 4; ++nt) {
        a1c[nt] = a[nt * 16 + lr];
        a2c[nt] = a[64 + nt * 16 + lr];
    }
#pragma unroll
    for (int r = 0; r < 4; ++r) {
        float s1 = 0.f, s2 = 0.f;
#pragma unroll
        for (int nt = 0; nt < 4; ++nt) {
            s1 += acc[nt][r] * a1c[nt];
            s2 += acc[nt][r] * a2c[nt];
        }
#pragma unroll
        for (int m = 1; m <= 8; m <<= 1) {
            s1 += __shfl_xor(s1, m, 64);
            s2 += __shfl_xor(s2, m, 64);
        }
        if (lr == 0) {
            s1p[row_base + lk * 4 + r] = s1 * LOG2E;
            s2p[row_base + lk * 4 + r] = s2 * LOG2E;
        }
    }
}

// ---------------------------------------------------------------------------
// K2: fused masked-softmax attention + PV with JIT mask streaming.
// 256 blocks x 512 thr (8 waves), block = 32 rows, 1 block/CU.
// Per body jt (one 256-j tile):
//   raw-barrier (lgkmcnt-only drain; vmcnt stays pending across bodies!)
//   ds_read mask(jt) from LDS dbuf | ballots+spread4 of adj(jt+1) -> dbuf
//   | issue adj loads (jt+2, coalesced i32x4, 2-deep named sets)
//   | issue z/s2 loads (jt+1) | PHA exp/mask | 8 MFMA.
// adj flight = 2 bodies (~1700cy > 900cy HBM latency); 8 streaming waves/CU.
// ---------------------------------------------------------------------------
#define LOADZ(Z0, Z1, Z2, Z3, jn) do {                                        \
    const u16* _zb = zq + (size_t)(((jn) + jb) >> 3) * 512;                   \
    Z0 = *(const u16x8*)(_zb +   0);                                          \
    Z1 = *(const u16x8*)(_zb + 128);                                          \
    Z2 = *(const u16x8*)(_zb + 256);                                          \
    Z3 = *(const u16x8*)(_zb + 384); } while (0)

#define LOADS2T(T0, T1, jn) do {                                              \
    T0 = *(const f32x4*)(s2r + (jn));                                         \
    T1 = *(const f32x4*)(s2r + (jn) + 4); } while (0)

#define LBLK(V0, V1, V2, V3, TT) do {                                         \
    V0 = *(const i32x4*)(aB + 0 * NN + (TT) * 256);                           \
    V1 = *(const i32x4*)(aB + 1 * NN + (TT) * 256);                           \
    V2 = *(const i32x4*)(aB + 2 * NN + (TT) * 256);                           \
    V3 = *(const i32x4*)(aB + 3 * NN + (TT) * 256); } while (0)

#define SROW(V, RI, MB) do {                                                  \
    const u64 _B0 = __ballot(V[0] != 0);                                      \
    const u64 _B1 = __ballot(V[1] != 0);                                      \
    const u64 _B2 = __ballot(V[2] != 0);                                      \
    const u64 _B3 = __ballot(V[3] != 0);                                      \
    if (l < 8) {                                                              \
        const u32 _w = spread4((u32)(_B0 >> (l * 8)) & 0xFFu)                 \
                     | (spread4((u32)(_B1 >> (l * 8)) & 0xFFu) << 1)          \
                     | (spread4((u32)(_B2 >> (l * 8)) & 0xFFu) << 2)          \
                     | (spread4((u32)(_B3 >> (l * 8)) & 0xFFu) << 3);         \
        maskt[MB][wv * 4 + (RI)][l] = _w;                                     \
    } } while (0)

#define SBLK(V0, V1, V2, V3, TT) do {                                         \
    const int _mb = (TT) & 1;                                                 \
    SROW(V0, 0, _mb); SROW(V1, 1, _mb);                                       \
    SROW(V2, 2, _mb); SROW(V3, 3, _mb); } while (0)

#define LOADBT(BB0, BB1, TT) do {                                             \
    BB0 = maskt[(TT) & 1][lr][wv];                                            \
    BB1 = maskt[(TT) & 1][lr + 16][wv]; } while (0)

// lgkmcnt-only drain + raw barrier: LDS writes ordered, vmcnt stays pending.
#define WAVEBAR() do {                                                        \
    asm volatile("s_waitcnt lgkmcnt(0)" ::: "memory");                        \
    __builtin_amdgcn_s_barrier();                                             \
    asm volatile("" ::: "memory"); } while (0)

#define PHA(WF, BW, S0, S1, S1R, DD) do {                                     \
    const u32 bsh = (BW) >> (lk * 8);                                         \
    _Pragma("unroll")                                                         \
    for (int i = 0; i < 4; ++i) {                                             \
        const float y = (S1R) + S0[i];                                        \
        float w = EXP2F(fmaxf(y, 0.2f * y));                                  \
        w = ((bsh >> i) & 1u) ? w : 0.0f;                                     \
        const __bf16 wb = (__bf16)w;                                          \
        WF[i] = wb; DD += (float)wb; }                                        \
    _Pragma("unroll")                                                         \
    for (int i = 0; i < 4; ++i) {                                             \
        const float y = (S1R) + S1[i];                                        \
        float w = EXP2F(fmaxf(y, 0.2f * y));                                  \
        w = ((bsh >> (4 + i)) & 1u) ? w : 0.0f;                               \
        const __bf16 wb = (__bf16)w;                                          \
        WF[4 + i] = wb; DD += (float)wb; } } while (0)

#define MFMA8(WF0, WF1, Z0, Z1, Z2, Z3) do {                                  \
    acc00 = __builtin_amdgcn_mfma_f32_16x16x32_bf16(WF0, __builtin_bit_cast(bf16x8, Z0), acc00, 0, 0, 0); \
    acc01 = __builtin_amdgcn_mfma_f32_16x16x32_bf16(WF0, __builtin_bit_cast(bf16x8, Z1), acc01, 0, 0, 0); \
    acc02 = __builtin_amdgcn_mfma_f32_16x16x32_bf16(WF0, __builtin_bit_cast(bf16x8, Z2), acc02, 0, 0, 0); \
    acc03 = __builtin_amdgcn_mfma_f32_16x16x32_bf16(WF0, __builtin_bit_cast(bf16x8, Z3), acc03, 0, 0, 0); \
    acc10 = __builtin_amdgcn_mfma_f32_16x16x32_bf16(WF1, __builtin_bit_cast(bf16x8, Z0), acc10, 0, 0, 0); \
    acc11 = __builtin_amdgcn_mfma_f32_16x16x32_bf16(WF1, __builtin_bit_cast(bf16x8, Z1), acc11, 0, 0, 0); \
    acc12 = __builtin_amdgcn_mfma_f32_16x16x32_bf16(WF1, __builtin_bit_cast(bf16x8, Z2), acc12, 0, 0, 0); \
    acc13 = __builtin_amdgcn_mfma_f32_16x16x32_bf16(WF1, __builtin_bit_cast(bf16x8, Z3), acc13, 0, 0, 0); } while (0)

#define BODYJ(CZ0,CZ1,CZ2,CZ3, NZ0,NZ1,NZ2,NZ3, SV0,SV1,SV2,SV3,              \
              LV0,LV1,LV2,LV3, SC0,SC1,SN0,SN1, JT, F_S, F_L, F_NXT) do {     \
    WAVEBAR();                                                                \
    u32 B0t, B1t;                                                             \
    LOADBT(B0t, B1t, JT);                                                     \
    if (F_S) SBLK(SV0, SV1, SV2, SV3, (JT) + 1);                              \
    if (F_L) LBLK(LV0, LV1, LV2, LV3, (JT) + 2);                              \
    if (F_NXT) { LOADZ(NZ0, NZ1, NZ2, NZ3, (JT) * 256 + 256);                 \
                 LOADS2T(SN0, SN1, (JT) * 256 + 256); }                       \
    bf16x8 wf0, wf1;                                                          \
    PHA(wf0, B0t, SC0, SC1, s1r0, d0);                                        \
    PHA(wf1, B1t, SC0, SC1, s1r1, d1);                                        \
    MFMA8(wf0, wf1, CZ0, CZ1, CZ2, CZ3); } while (0)

__global__ __launch_bounds__(512, 2) void k_attn(
        const int* __restrict__ adj, const u16* __restrict__ zt,
        const float* __restrict__ s1p, const float* __restrict__ s2p,
        const float* __restrict__ bias, float* __restrict__ out)
{
    __shared__ float apart[8][32][64];   // 64 KiB (epilogue only)
    __shared__ float dpart[8][4][32];    // 4 KiB
    __shared__ u32   maskt[2][32][9];    // 2.25 KiB mask dbuf (pad 9: no conflicts)

    const int t  = threadIdx.x;
    const int wv = t >> 6, l = t & 63;
    const int lr = l & 15, lk = l >> 4;
    const int row0 = blockIdx.x * 32;
    const int jb = wv * 32 + lk * 8;     // wave+lane j offset within 256-tile

    const float s1r0 = s1p[row0 + lr];
    const float s1r1 = s1p[row0 + 16 + lr];
    const float* s2r  = s2p + jb;
    const u16*   zq   = zt + lr * 8;
    const int*   aB   = adj + (size_t)(row0 + wv * 4) * NN + l * 4; // wave's 4 rows

    f32x4 acc00{}, acc01{}, acc02{}, acc03{};
    f32x4 acc10{}, acc11{}, acc12{}, acc13{};
    float d0 = 0.f, d1 = 0.f;

    u16x8 zU0, zU1, zU2, zU3, zV0, zV1, zV2, zV3;
    i32x4 qA0, qA1, qA2, qA3, qB0, qB1, qB2, qB3;   // adj staging, 2-deep
    f32x4 sA0, sA1, sB0, sB1;

    // prologue: z/s2 tile0; adj tiles 0,1; mask tile0 -> buf0
    LOADZ(zU0, zU1, zU2, zU3, 0);
    LOADS2T(sA0, sA1, 0);
    LBLK(qA0, qA1, qA2, qA3, 0);
    LBLK(qB0, qB1, qB2, qB3, 1);
    SBLK(qA0, qA1, qA2, qA3, 0);

    for (int jt = 0; jt < 30; jt += 2) {
        BODYJ(zU0, zU1, zU2, zU3, zV0, zV1, zV2, zV3,
              qB0, qB1, qB2, qB3, qA0, qA1, qA2, qA3,
              sA0, sA1, sB0, sB1, jt, 1, 1, 1);
        BODYJ(zV0, zV1, zV2, zV3, zU0, zU1, zU2, zU3,
              qA0, qA1, qA2, qA3, qB0, qB1, qB2, qB3,
              sB0, sB1, sA0, sA1, jt + 1, 1, 1, 1);
    }
    BODYJ(zU0, zU1, zU2, zU3, zV0, zV1, zV2, zV3,
          qB0, qB1, qB2, qB3, qA0, qA1, qA2, qA3,
          sA0, sA1, sB0, sB1, 30, 1, 0, 1);
    BODYJ(zV0, zV1, zV2, zV3, zU0, zU1, zU2, zU3,
          qA0, qA1, qA2, qA3, qB0, qB1, qB2, qB3,
          sB0, sB1, sA0, sA1, 31, 0, 0, 0);

    // ---------------- epilogue: cross-wave j-slice reduction -----------------
    dpart[wv][lk][lr]      = d0;
    dpart[wv][lk][16 + lr] = d1;
#pragma unroll
    for (int r = 0; r < 4; ++r) {
        apart[wv][lk * 4 + r][ 0 + lr] = acc00[r];
        apart[wv][lk * 4 + r][16 + lr] = acc01[r];
        apart[wv][lk * 4 + r][32 + lr] = acc02[r];
        apart[wv][lk * 4 + r][48 + lr] = acc03[r];
        apart[wv][16 + lk * 4 + r][ 0 + lr] = acc10[r];
        apart[wv][16 + lk * 4 + r][16 + lr] = acc11[r];
        apart[wv][16 + lk * 4 + r][32 + lr] = acc12[r];
        apart[wv][16 + lk * 4 + r][48 + lr] = acc13[r];
    }
    __syncthreads();

    {
        const int r  = t >> 4;           // 0..31
        const int c0 = (t & 15) * 4;
        float den = 0.f;
#pragma unroll
        for (int q = 0; q < 32; ++q)
            den += dpart[q >> 2][q & 3][r];
        f32x4 val = {};
#pragma unroll
        for (int q = 0; q < 8; ++q)
            val += *(const f32x4*)&apart[q][r][c0];
        const f32x4 bv = *(const f32x4*)(bias + c0);
        const f32x4 o = val * (1.0f / den) + bv;
        *(f32x4*)(out + (size_t)(row0 + r) * FOUT + c0) = o;
    }
}

// ---------------------------------------------------------------------------
extern "C" void kernel_launch(void* const* d_in, const int* in_sizes, int n_in,
                              void* d_out, int out_size, void* d_ws, size_t ws_size,
                              hipStream_t stream) {
    const float* input = (const float*)d_in[0];
    const int*   adj   = (const int*)d_in[1];
    const float* W     = (const float*)d_in[2];
    const float* a     = (const float*)d_in[3];
    const float* bias  = (const float*)d_in[4];
    float* out = (float*)d_out;

    char* ws = (char*)d_ws;
    u16*   wt_hi = (u16*)ws;   ws += FIN * FOUT * sizeof(u16);
    u16*   wt_lo = (u16*)ws;   ws += FIN * FOUT * sizeof(u16);
    float* s1p   = (float*)ws; ws += NN * sizeof(float);
    float* s2p   = (float*)ws; ws += NN * sizeof(float);
    u16*   zt    = (u16*)ws;   ws += (size_t)NN * FOUT * sizeof(u16);

    k_wt   <<<dim3(128), dim3(256), 0, stream>>>(W, wt_hi, wt_lo);
    k_zgemm<<<dim3(512), dim3(128), 0, stream>>>(input, wt_hi, wt_lo, a, zt, s1p, s2p);
    k_attn <<<dim3(256), dim3(512), 0, stream>>>(adj, zt, s1p, s2p, bias, out);
}